// Round 9
// baseline (300.635 us; speedup 1.0000x reference)
//
#include <hip/hip_runtime.h>

#define D 128   // feature dim
#define H 64    // hidden dim of classifier
#define NS 8    // graph slots per aggpool block

typedef __attribute__((ext_vector_type(8))) short bf16x8;
typedef __attribute__((ext_vector_type(4))) float f32x4;

// ---------- bf16 helpers (bit-level, RNE) ----------

__device__ __forceinline__ unsigned int bf16_rne(float f) {
    unsigned int u = __float_as_uint(f);
    u += 0x7fffu + ((u >> 16) & 1u);
    return u >> 16;
}
__device__ __forceinline__ unsigned int pack_bf16(float a, float b) {
    return bf16_rne(a) | (bf16_rne(b) << 16);
}
__device__ __forceinline__ float bf16_lo(unsigned int u) { return __uint_as_float(u << 16); }
__device__ __forceinline__ float bf16_hi(unsigned int u) { return __uint_as_float(u & 0xffff0000u); }
__device__ __forceinline__ float bf16_val(unsigned int h) { return __uint_as_float(h << 16); }

__device__ __forceinline__ bf16x8 as_bf16x8(uint4 u) {
    union { uint4 u; bf16x8 b; } x; x.u = u; return x.b;
}

// ---------- wprep: W1/W2/W3 -> fragment-ordered double-bf16; zero cnt/state/hist/binctr/pooled + hb zero-rows ----------

static __global__ __launch_bounds__(256) void wprep_k(
        const float* __restrict__ W1, const float* __restrict__ W2, const float* __restrict__ W3,
        unsigned int* __restrict__ Bfrag,    // [6][8192]: h1,l1,h2,l2,h3,l3
        int* __restrict__ cnt, int zcount4,
        unsigned int* __restrict__ zrowA, unsigned int* __restrict__ zrowB) {
    int gid = blockIdx.x * 256 + threadIdx.x;
    for (int i = gid; i < zcount4; i += 24 * 256)
        ((uint4*)cnt)[i] = make_uint4(0u, 0u, 0u, 0u);
    if (blockIdx.x == 0 && threadIdx.x < 32) {
        unsigned int* zr = (threadIdx.x < 16) ? zrowA : zrowB;   // zero row n of hbA / hbB
        *(uint4*)&zr[(threadIdx.x & 15) * 4] = make_uint4(0u, 0u, 0u, 0u);
    }

    const int wsel = blockIdx.x >> 3;
    const float* W = (wsel == 0) ? W1 : (wsel == 1) ? W2 : W3;
    unsigned int* Bh = Bfrag + (size_t)(2 * wsel) * 8192;
    unsigned int* Bl = Bh + 8192;
    int tt = (blockIdx.x & 7) * 256 + threadIdx.x;   // 0..2047
    int lane = tt & 63, kc = (tt >> 6) & 3, c = tt >> 8;
    int m = lane & 15, quad = lane >> 4;
    int col = c * 16 + m;
    int k0 = kc * 32 + quad * 8;
    unsigned int h4[4], l4[4];
#pragma unroll
    for (int dd = 0; dd < 4; dd++) {
        float w0 = W[(k0 + 2 * dd) * D + col];
        float w1 = W[(k0 + 2 * dd + 1) * D + col];
        unsigned int h0 = bf16_rne(w0), h1 = bf16_rne(w1);
        unsigned int L0 = bf16_rne(w0 - bf16_val(h0));
        unsigned int L1 = bf16_rne(w1 - bf16_val(h1));
        h4[dd] = h0 | (h1 << 16);
        l4[dd] = L0 | (L1 << 16);
    }
    int base = ((c * 4 + kc) * 64 + lane) * 4;
    *(uint4*)&Bh[base] = make_uint4(h4[0], h4[1], h4[2], h4[3]);
    *(uint4*)&Bl[base] = make_uint4(l4[0], l4[1], l4[2], l4[3]);
}

// ---------- FAT1: gemm1 (Bh in 32KB LDS, Bl from L2) ∥ pass1 histogram/rank blocks (r6-proven) ----------

static __global__ __launch_bounds__(512) void fat1_k(
        const float* __restrict__ x, const unsigned int* __restrict__ Bfrag,
        unsigned int* __restrict__ hb, int n, int gb,
        const int* __restrict__ ei, int E,
        int* __restrict__ cnt, int* __restrict__ rank) {
    __shared__ uint4 Bs[2048];           // 32 KB: W1 hi fragments only
    const int tid = threadIdx.x;
    if ((int)blockIdx.x >= gb) {     // ---- pass1: 4 edges/thread, 2048/block ----
        int e0 = (((int)blockIdx.x - gb) * 512 + tid) * 4;
        if (((E & 3) == 0) && e0 + 3 < E) {
            int4 d = *(const int4*)&ei[E + e0];
            int4 r;
            r.x = atomicAdd(&cnt[d.x], 1);
            r.y = atomicAdd(&cnt[d.y], 1);
            r.z = atomicAdd(&cnt[d.z], 1);
            r.w = atomicAdd(&cnt[d.w], 1);
            *(int4*)&rank[e0] = r;
        } else {
            for (int e = e0; e < E && e < e0 + 4; e++)
                rank[e] = atomicAdd(&cnt[ei[E + e]], 1);
        }
        return;
    }
    // stage W1 hi fragments (32 KB) into LDS; lo stays in global (L2-hot)
    {
        const uint4* Bg = (const uint4*)Bfrag;
#pragma unroll
        for (int i = 0; i < 4; i++)
            Bs[tid + i * 512] = Bg[tid + i * 512];
    }
    // ---- gemm1: MFMA double-bf16, unscaled; 8 waves x 16 rows ----
    const int g = blockIdx.x;
    const int w = tid >> 6;              // 0..7
    const int lane = tid & 63;
    const int m = lane & 15, quad = lane >> 4;
    const int arow = g * 128 + w * 16 + m;
    const bool rok = arow < n;
    uint4 Ah[4], Al[4];
#pragma unroll
    for (int kc = 0; kc < 4; kc++) {
        float4 f0 = make_float4(0.f, 0.f, 0.f, 0.f), f1 = f0;
        if (rok) {
            f0 = *(const float4*)&x[(size_t)arow * D + kc * 32 + quad * 8];
            f1 = *(const float4*)&x[(size_t)arow * D + kc * 32 + quad * 8 + 4];
        }
        unsigned int h0 = bf16_rne(f0.x), h1 = bf16_rne(f0.y), h2 = bf16_rne(f0.z), h3 = bf16_rne(f0.w);
        unsigned int h4 = bf16_rne(f1.x), h5 = bf16_rne(f1.y), h6 = bf16_rne(f1.z), h7 = bf16_rne(f1.w);
        Ah[kc] = make_uint4(h0 | (h1 << 16), h2 | (h3 << 16), h4 | (h5 << 16), h6 | (h7 << 16));
        unsigned int g0 = bf16_rne(f0.x - bf16_val(h0)), g1 = bf16_rne(f0.y - bf16_val(h1));
        unsigned int g2 = bf16_rne(f0.z - bf16_val(h2)), g3 = bf16_rne(f0.w - bf16_val(h3));
        unsigned int g4 = bf16_rne(f1.x - bf16_val(h4)), g5 = bf16_rne(f1.y - bf16_val(h5));
        unsigned int g6 = bf16_rne(f1.z - bf16_val(h6)), g7 = bf16_rne(f1.w - bf16_val(h7));
        Al[kc] = make_uint4(g0 | (g1 << 16), g2 | (g3 << 16), g4 | (g5 << 16), g6 | (g7 << 16));
    }
    __syncthreads();
    const int erow0 = g * 128 + w * 16 + quad * 4;
    unsigned short* out = (unsigned short*)hb;
    const unsigned int* Blg = Bfrag + 8192;
#pragma unroll
    for (int c = 0; c < 8; c++) {
        f32x4 acc = {0.f, 0.f, 0.f, 0.f};
#pragma unroll
        for (int kc = 0; kc < 4; kc++) {
            uint4 bh = Bs[(c * 4 + kc) * 64 + lane];
            uint4 bl = *(const uint4*)&Blg[((c * 4 + kc) * 64 + lane) * 4];
            acc = __builtin_amdgcn_mfma_f32_16x16x32_bf16(as_bf16x8(Ah[kc]), as_bf16x8(bh), acc, 0, 0, 0);
            acc = __builtin_amdgcn_mfma_f32_16x16x32_bf16(as_bf16x8(Ah[kc]), as_bf16x8(bl), acc, 0, 0, 0);
            acc = __builtin_amdgcn_mfma_f32_16x16x32_bf16(as_bf16x8(Al[kc]), as_bf16x8(bh), acc, 0, 0, 0);
        }
        int col = c * 16 + m;
#pragma unroll
        for (int r = 0; r < 4; r++) {
            int rr = erow0 + r;
            if (rr < n)
                out[(size_t)rr * D + col] = (unsigned short)bf16_rne(acc[r]);
        }
    }
}

// ---------- Single-dispatch exclusive scan (decoupled lookback) + dinv + degree histogram ----------

static __global__ __launch_bounds__(256) void scan_k(
        const int* __restrict__ cnt, int n, int* __restrict__ state,
        int* __restrict__ rowptr, float* __restrict__ dinv,
        int* __restrict__ hist) {
    __shared__ int s[256];
    __shared__ int lh[64];
    __shared__ int sprefix;
    const int b = blockIdx.x;
    const int i = b * 256 + threadIdx.x;
    if (threadIdx.x < 64) lh[threadIdx.x] = 0;
    int v = (i < n) ? cnt[i] : 0;
    if (i < n) dinv[i] = rsqrtf((float)v + 1.0f);   // +1 self loop; deg >= 1 always
    s[threadIdx.x] = v;
    __syncthreads();
    if (i < n) atomicAdd(&lh[v < 63 ? v : 63], 1);
    for (int off = 1; off < 256; off <<= 1) {
        int t = ((int)threadIdx.x >= off) ? s[threadIdx.x - off] : 0;
        __syncthreads();
        s[threadIdx.x] += t;
        __syncthreads();
    }
    int incl = s[threadIdx.x];
    int total = s[255];
    if (threadIdx.x == 0) {
        if (b == 0) {
            atomicExch(&state[0], (total << 2) | 2);
            sprefix = 0;
        } else {
            atomicExch(&state[b], (total << 2) | 1);
            int run = 0;
            for (int j = b - 1; j >= 0; j--) {
                int p;
                do { p = atomicAdd(&state[j], 0); } while ((p & 3) == 0);
                run += (p >> 2);
                if ((p & 3) == 2) break;
            }
            atomicExch(&state[b], ((run + total) << 2) | 2);
            sprefix = run;
        }
    }
    __syncthreads();
    int pre = sprefix;
    if (i < n) {
        rowptr[i] = pre + incl - v;
        if (i == n - 1) rowptr[n] = pre + incl;
    }
    if (threadIdx.x < 64) {
        int c = lh[threadIdx.x];
        if (c) atomicAdd(&hist[threadIdx.x], c);
    }
}

// ---------- FAT2b: pass2 scatter ∥ in-place dinv scale of hbA ∥ perm counting-sort (r6-proven) ----------

static __global__ __launch_bounds__(256) void fat2b_k(
        unsigned int* __restrict__ hb, const float* __restrict__ dinv, int n,
        int p2b, int sb,
        const int* __restrict__ ei, int E,
        const int* __restrict__ rank, const int* __restrict__ rowptr,
        int* __restrict__ csr_src,
        const int* __restrict__ cnt, const int* __restrict__ hist,
        int* __restrict__ binctr, int* __restrict__ perm) {
    const int tid = threadIdx.x;
    int bb = (int)blockIdx.x;
    if (bb < p2b) {          // ---- pass2: no-atomic scatter, 2 edges/thread ----
        int e0 = (bb * 256 + tid) * 2;
        if (e0 + 1 < E) {
            int2 s2 = *(const int2*)&ei[e0];
            int2 d2 = *(const int2*)&ei[E + e0];
            int2 r2 = *(const int2*)&rank[e0];
            csr_src[rowptr[d2.x] + r2.x] = s2.x;
            csr_src[rowptr[d2.y] + r2.y] = s2.y;
        } else if (e0 < E) {
            csr_src[rowptr[ei[E + e0]] + rank[e0]] = ei[e0];
        }
        return;
    }
    bb -= p2b;
    if (bb < sb) {           // ---- scale: hbA row r *= dinv[r] (in place, uint4 = 8 bf16) ----
        int i4 = bb * 256 + tid;
        if (i4 < n * 16) {
            float d = dinv[i4 >> 4];
            uint4 v = ((const uint4*)hb)[i4];
            v.x = pack_bf16(bf16_lo(v.x) * d, bf16_hi(v.x) * d);
            v.y = pack_bf16(bf16_lo(v.y) * d, bf16_hi(v.y) * d);
            v.z = pack_bf16(bf16_lo(v.z) * d, bf16_hi(v.z) * d);
            v.w = pack_bf16(bf16_lo(v.w) * d, bf16_hi(v.w) * d);
            ((uint4*)hb)[i4] = v;
        }
        return;
    }
    bb -= sb;
    // ---- permscatter: descending-degree counting sort (two-level, low contention) ----
    __shared__ int loff[64], lcnt[64], lbase[64];
    if (tid < 64) {
        int ssum = 0;                         // descending: heavy bins first (LPT)
        for (int j = tid + 1; j < 64; j++) ssum += hist[j];
        loff[tid] = ssum;
        lcnt[tid] = 0;
    }
    __syncthreads();
    int i = bb * 256 + tid;
    int bin = 0, lrank = 0;
    if (i < n) {
        int dg = cnt[i];
        bin = dg < 63 ? dg : 63;
        lrank = atomicAdd(&lcnt[bin], 1);
    }
    __syncthreads();
    if (tid < 64 && lcnt[tid]) lbase[tid] = atomicAdd(&binctr[tid], lcnt[tid]);
    __syncthreads();
    if (i < n) perm[loff[bin] + lbase[bin] + lrank] = i;
}

// ---------- gather core: round-6 form (bulk int4 idx + sched_barrier-pinned gathers) ----------

__device__ __forceinline__ void gather_accum8(
        const unsigned int* __restrict__ hbin, const int* __restrict__ csr,
        int beg, int deg, int n, int l,
        float& a0, float& a1, float& a2, float& a3,
        float& a4, float& a5, float& a6, float& a7) {
    const int nbat = (deg + 7) >> 3;
    int4 iA = *(const int4*)&csr[beg];        // pad-safe (csr has +64 ints slack)
    int4 iB = *(const int4*)&csr[beg + 4];
    for (int t = 0; t < nbat; t++) {
        const int q = t * 8;
        int s[8];
        s[0] = (q + 0 < deg) ? iA.x : n;
        s[1] = (q + 1 < deg) ? iA.y : n;
        s[2] = (q + 2 < deg) ? iA.z : n;
        s[3] = (q + 3 < deg) ? iA.w : n;
        s[4] = (q + 4 < deg) ? iB.x : n;
        s[5] = (q + 5 < deg) ? iB.y : n;
        s[6] = (q + 6 < deg) ? iB.z : n;
        s[7] = (q + 7 < deg) ? iB.w : n;
        uint4 v[8];
#pragma unroll
        for (int i = 0; i < 8; i++)
            v[i] = *(const uint4*)&hbin[(size_t)s[i] * 64 + l * 4];
        iA = *(const int4*)&csr[beg + q + 8];     // prefetch next batch (pad-safe)
        iB = *(const int4*)&csr[beg + q + 12];
        __builtin_amdgcn_sched_barrier(0);
#pragma unroll
        for (int i = 0; i < 8; i++) {
            a0 += bf16_lo(v[i].x); a1 += bf16_hi(v[i].x);
            a2 += bf16_lo(v[i].y); a3 += bf16_hi(v[i].y);
            a4 += bf16_lo(v[i].z); a5 += bf16_hi(v[i].z);
            a6 += bf16_lo(v[i].w); a7 += bf16_hi(v[i].w);
        }
    }
}

// ---------- FUSED agg + MFMA gemm: quarter-wave gathers (4 nodes/wave, uint4 = 16B/lane) ----------

static __global__ __launch_bounds__(256) void aggemm_k(
        const unsigned int* __restrict__ hbin,        // (n+1) rows, row n == 0
        const float* __restrict__ dinv,
        const int* __restrict__ rowptr, const int* __restrict__ csr,
        const int* __restrict__ perm,
        const float* __restrict__ bias,               // bias of PREV conv
        const unsigned int* __restrict__ Bh,          // next W, frag-ordered hi
        const unsigned int* __restrict__ Bl,          //             lo
        unsigned int* __restrict__ hbout, int n) {
    __shared__ unsigned int xs[16 * 68];   // 16 rows x 64 uints + 4 pad
    __shared__ int pms[16];
    __shared__ float pdv[16];
    const int tid = threadIdx.x;
    const int wv = tid >> 6;               // 0..3
    const int lane = tid & 63;
    const int l = lane & 15;               // lane in quarter
    const int lslot = wv * 4 + (lane >> 4);  // local node slot 0..15
    const int slot = blockIdx.x * 16 + lslot;
    const int node = (slot < n) ? perm[slot] : -1;
    if (l == 0) {
        pms[lslot] = node;
        pdv[lslot] = (node >= 0) ? dinv[node] : 0.f;
    }

    if (node >= 0) {
        const int beg = rowptr[node];
        const int deg = rowptr[node + 1] - beg;
        float a0 = 0.f, a1 = 0.f, a2 = 0.f, a3 = 0.f;
        float a4 = 0.f, a5 = 0.f, a6 = 0.f, a7 = 0.f;
        gather_accum8(hbin, csr, beg, deg, n, l, a0, a1, a2, a3, a4, a5, a6, a7);
        uint4 hv = *(const uint4*)&hbin[(size_t)node * 64 + l * 4];
        a0 += bf16_lo(hv.x); a1 += bf16_hi(hv.x);
        a2 += bf16_lo(hv.y); a3 += bf16_hi(hv.y);
        a4 += bf16_lo(hv.z); a5 += bf16_hi(hv.z);
        a6 += bf16_lo(hv.w); a7 += bf16_hi(hv.w);
        const float di = dinv[node];
        float4 b0 = *(const float4*)&bias[l * 8];
        float4 b1 = *(const float4*)&bias[l * 8 + 4];
        float o0 = fmaxf(fmaf(di, a0, b0.x), 0.f);
        float o1 = fmaxf(fmaf(di, a1, b0.y), 0.f);
        float o2 = fmaxf(fmaf(di, a2, b0.z), 0.f);
        float o3 = fmaxf(fmaf(di, a3, b0.w), 0.f);
        float o4 = fmaxf(fmaf(di, a4, b1.x), 0.f);
        float o5 = fmaxf(fmaf(di, a5, b1.y), 0.f);
        float o6 = fmaxf(fmaf(di, a6, b1.z), 0.f);
        float o7 = fmaxf(fmaf(di, a7, b1.w), 0.f);
        uint4 pw;
        pw.x = pack_bf16(o0, o1);
        pw.y = pack_bf16(o2, o3);
        pw.z = pack_bf16(o4, o5);
        pw.w = pack_bf16(o6, o7);
        *(uint4*)&xs[lslot * 68 + 4 * l] = pw;
    } else {
        *(uint4*)&xs[lslot * 68 + 4 * l] = make_uint4(0u, 0u, 0u, 0u);
    }
    __syncthreads();

    // ---- gemm phase: wave wv -> col groups c = 2wv, 2wv+1 ----
    const int m = lane & 15, quad = lane >> 4;
    uint4 A[4];
#pragma unroll
    for (int kc = 0; kc < 4; kc++)
        A[kc] = *(const uint4*)&xs[m * 68 + kc * 16 + quad * 4];
    unsigned short* out = (unsigned short*)hbout;
#pragma unroll
    for (int cc = 0; cc < 2; cc++) {
        const int c = wv * 2 + cc;
        f32x4 acc = {0.f, 0.f, 0.f, 0.f};
#pragma unroll
        for (int kc = 0; kc < 4; kc++) {
            int base = ((c * 4 + kc) * 64 + lane) * 4;
            uint4 bh = *(const uint4*)&Bh[base];
            uint4 bl = *(const uint4*)&Bl[base];
            acc = __builtin_amdgcn_mfma_f32_16x16x32_bf16(as_bf16x8(A[kc]), as_bf16x8(bh), acc, 0, 0, 0);
            acc = __builtin_amdgcn_mfma_f32_16x16x32_bf16(as_bf16x8(A[kc]), as_bf16x8(bl), acc, 0, 0, 0);
        }
        const int col = c * 16 + m;
#pragma unroll
        for (int r = 0; r < 4; r++) {
            int ls = quad * 4 + r;
            int nd = pms[ls];
            if (nd >= 0)
                out[(size_t)nd * D + col] = (unsigned short)bf16_rne(acc[r] * pdv[ls]);
        }
    }
}

// ---------- FUSED layer-3 agg + mean-pool partials ----------
// 64 consecutive nodes/block (batch-sorted -> few graphs/block). Node outputs stay
// f32 and accumulate into an LDS partial-pool (NS graph slots x 128 feats), flushed
// with one global atomicAdd per nonzero (slot,feat) -> ~300K fire-and-forget atomics
// to 64K addresses. Deletes the 12.8MB hbB write + poolcls re-read.

static __global__ __launch_bounds__(256) void aggpool_k(
        const unsigned int* __restrict__ hb,          // hbA, (n+1) rows, row n == 0
        const float* __restrict__ dinv,
        const int* __restrict__ rowptr, const int* __restrict__ csr,
        const float* __restrict__ bias,               // b3
        const int* __restrict__ batch,
        float* __restrict__ pooled, int n, int G_) {
    __shared__ float plocal[NS * D];
    __shared__ int sg0;
    const int tid = threadIdx.x;
    for (int i = tid; i < NS * D; i += 256) plocal[i] = 0.f;
    const int base = blockIdx.x * 64;
    if (tid == 0) sg0 = (base < n) ? batch[base] : 0;
    __syncthreads();
    const int g0 = sg0;
    const int wv = tid >> 6;
    const int lane = tid & 63;
    const int l = lane & 15;
    const int q = lane >> 4;

    for (int it = 0; it < 4; it++) {
        const int node = base + it * 16 + wv * 4 + q;
        if (node < n) {
            const int beg = rowptr[node];
            const int deg = rowptr[node + 1] - beg;
            float a0 = 0.f, a1 = 0.f, a2 = 0.f, a3 = 0.f;
            float a4 = 0.f, a5 = 0.f, a6 = 0.f, a7 = 0.f;
            gather_accum8(hb, csr, beg, deg, n, l, a0, a1, a2, a3, a4, a5, a6, a7);
            uint4 hv = *(const uint4*)&hb[(size_t)node * 64 + l * 4];
            a0 += bf16_lo(hv.x); a1 += bf16_hi(hv.x);
            a2 += bf16_lo(hv.y); a3 += bf16_hi(hv.y);
            a4 += bf16_lo(hv.z); a5 += bf16_hi(hv.z);
            a6 += bf16_lo(hv.w); a7 += bf16_hi(hv.w);
            const float di = dinv[node];
            float4 b0 = *(const float4*)&bias[l * 8];
            float4 b1 = *(const float4*)&bias[l * 8 + 4];
            float o0 = fmaxf(fmaf(di, a0, b0.x), 0.f);
            float o1 = fmaxf(fmaf(di, a1, b0.y), 0.f);
            float o2 = fmaxf(fmaf(di, a2, b0.z), 0.f);
            float o3 = fmaxf(fmaf(di, a3, b0.w), 0.f);
            float o4 = fmaxf(fmaf(di, a4, b1.x), 0.f);
            float o5 = fmaxf(fmaf(di, a5, b1.y), 0.f);
            float o6 = fmaxf(fmaf(di, a6, b1.z), 0.f);
            float o7 = fmaxf(fmaf(di, a7, b1.w), 0.f);
            const int gl = batch[node] - g0;
            if (gl < NS) {
                float* p = &plocal[gl * D + l * 8];
                atomicAdd(&p[0], o0); atomicAdd(&p[1], o1);
                atomicAdd(&p[2], o2); atomicAdd(&p[3], o3);
                atomicAdd(&p[4], o4); atomicAdd(&p[5], o5);
                atomicAdd(&p[6], o6); atomicAdd(&p[7], o7);
            } else {                      // rare fallback: tiny graphs spanning > NS
                float* p = &pooled[(size_t)(g0 + gl) * D + l * 8];
                atomicAdd(&p[0], o0); atomicAdd(&p[1], o1);
                atomicAdd(&p[2], o2); atomicAdd(&p[3], o3);
                atomicAdd(&p[4], o4); atomicAdd(&p[5], o5);
                atomicAdd(&p[6], o6); atomicAdd(&p[7], o7);
            }
        }
    }
    __syncthreads();
    for (int i = tid; i < NS * D; i += 256) {
        float v = plocal[i];
        if (v != 0.f) {
            int gl = i >> 7, f = i & (D - 1);
            int gg = g0 + gl;
            if (gg < G_) atomicAdd(&pooled[(size_t)gg * D + f], v);
        }
    }
}

// ---------- Classifier: one wave per graph ----------

static __global__ __launch_bounds__(64) void cls_k(
        const float* __restrict__ pooled,
        const int* __restrict__ batch, int n,
        const float* __restrict__ Wc, const float* __restrict__ bc,
        const float* __restrict__ Wo, const float* __restrict__ bo,
        float* __restrict__ out) {
    const int g = blockIdx.x;
    const int t = threadIdx.x;
    int lo = 0, hi = n;
    while (lo < hi) { int m = (lo + hi) >> 1; if (batch[m] < g) lo = m + 1; else hi = m; }
    int start = lo;
    hi = n;
    while (lo < hi) { int m = (lo + hi) >> 1; if (batch[m] < g + 1) lo = m + 1; else hi = m; }
    const float invc = 1.0f / fmaxf((float)(lo - start), 1.0f);
    __shared__ float sp[D];
    sp[t]      = pooled[(size_t)g * D + t] * invc;
    sp[t + 64] = pooled[(size_t)g * D + 64 + t] * invc;
    __syncthreads();
    float z = bc[t];
#pragma unroll
    for (int k = 0; k < D; k++) z = fmaf(sp[k], Wc[k * H + t], z);
    z = fmaxf(z, 0.f);
    float v = z * Wo[t];
    for (int off = 32; off > 0; off >>= 1) v += __shfl_down(v, off);
    if (t == 0) out[g] = v + bo[0];
}

// ---------- Orchestration ----------

extern "C" void kernel_launch(void* const* d_in, const int* in_sizes, int n_in,
                              void* d_out, int out_size, void* d_ws, size_t ws_size,
                              hipStream_t stream) {
    const float* x     = (const float*)d_in[0];
    const int*   ei    = (const int*)d_in[1];
    const int*   batch = (const int*)d_in[2];
    const float* W1 = (const float*)d_in[3];
    const float* b1 = (const float*)d_in[4];
    const float* W2 = (const float*)d_in[5];
    const float* b2 = (const float*)d_in[6];
    const float* W3 = (const float*)d_in[7];
    const float* b3 = (const float*)d_in[8];
    const float* Wc = (const float*)d_in[9];
    const float* bc = (const float*)d_in[10];
    const float* Wo = (const float*)d_in[11];
    const float* bo = (const float*)d_in[12];

    const int n = in_sizes[0] / D;
    const int E = in_sizes[1] / 2;
    const int G = out_size;

    char* ws = (char*)d_ws;
    size_t off = 0;
    auto alloc = [&](size_t bytes) -> void* {
        void* p = ws + off;
        off = (off + bytes + 255) & ~(size_t)255;
        return p;
    };
    // contiguous zero region: cnt(n) | state(256) | hist(64) | binctr(64) | pooled(G*D floats)
    int*   cnt     = (int*)alloc((size_t)(n + 384 + G * D) * 4 + 4096);
    int*   state   = cnt + n;
    int*   hist    = state + 256;
    int*   binctr  = hist + 64;
    float* pooled  = (float*)(binctr + 64);
    int*   rowptr  = (int*)alloc((size_t)(n + 1) * 4);
    float* dinv    = (float*)alloc((size_t)n * 4);
    int*   rank    = (int*)alloc((size_t)E * 4);
    int*   csr_src = (int*)alloc((size_t)E * 4 + 256);   // +64 ints pad for bulk idx loads
    int*   perm    = (int*)alloc((size_t)n * 4);
    unsigned int* hbA = (unsigned int*)alloc((size_t)(n + 1) * (D / 2) * 4);  // +1 zero row
    unsigned int* hbB = (unsigned int*)alloc((size_t)(n + 1) * (D / 2) * 4);
    unsigned int* Bfrag = (unsigned int*)alloc(6 * 8192 * 4);                 // h1,l1,h2,l2,h3,l3
    (void)ws_size; (void)n_in;

    const int NB = (n + 255) / 256;
    const int GB = (n + 127) / 128;                 // fat1 gemm blocks (128 rows each)
    const int P1 = (E + 2047) / 2048;               // fat1 pass1 blocks (512 thr x 4 edges)
    const int P2 = (E + 511) / 512;
    const int SB = (n * 16 + 255) / 256;            // scale blocks (uint4 per thread)
    const int PP = (n + 255) / 256;
    const int ag16 = (n + 15) / 16;
    const int AP = (n + 63) / 64;                   // aggpool blocks (64 nodes each)
    const int zcount4 = (n + 384 + G * D + 3) / 4;

    // W prep + zero cnt/state/hist/binctr/pooled + zero rows n of hbA/hbB
    wprep_k<<<24, 256, 0, stream>>>(W1, W2, W3, Bfrag, cnt, zcount4,
                                    hbA + (size_t)n * 64, hbB + (size_t)n * 64);

    // gemm1 (Bh in LDS, Bl from L2) ∥ pass1 histogram+rank
    fat1_k<<<GB + P1, 512, 0, stream>>>(x, Bfrag, hbA, n, GB, ei, E, cnt, rank);

    // rowptr scan + dinv + degree-bin histogram
    scan_k<<<NB, 256, 0, stream>>>(cnt, n, state, rowptr, dinv, hist);

    // pass2 scatter ∥ hbA in-place dinv scale ∥ degree counting-sort perm
    fat2b_k<<<P2 + SB + PP, 256, 0, stream>>>(hbA, dinv, n, P2, SB,
                                              ei, E, rank, rowptr, csr_src,
                                              cnt, hist, binctr, perm);

    // layer boundaries: fused agg(prev) + gemm(next W); all pre-scaled bf16
    aggemm_k<<<ag16, 256, 0, stream>>>(hbA, dinv, rowptr, csr_src, perm, b1,
                                       Bfrag + 2 * 8192, Bfrag + 3 * 8192, hbB, n);
    aggemm_k<<<ag16, 256, 0, stream>>>(hbB, dinv, rowptr, csr_src, perm, b2,
                                       Bfrag + 4 * 8192, Bfrag + 5 * 8192, hbA, n);

    // fused layer-3 agg + mean-pool partials, then classifier
    aggpool_k<<<AP, 256, 0, stream>>>(hbA, dinv, rowptr, csr_src, b3,
                                      batch, pooled, n, G);
    cls_k<<<G, 64, 0, stream>>>(pooled, batch, n, Wc, bc, Wo, bo, (float*)d_out);
}

// Round 10
// 278.983 us; speedup vs baseline: 1.0776x; 1.0776x over previous
//
#include <hip/hip_runtime.h>

#define D 128   // feature dim
#define H 64    // hidden dim of classifier

typedef __attribute__((ext_vector_type(8))) short bf16x8;
typedef __attribute__((ext_vector_type(4))) float f32x4;

// ---------- bf16 helpers (bit-level, RNE) ----------

__device__ __forceinline__ unsigned int bf16_rne(float f) {
    unsigned int u = __float_as_uint(f);
    u += 0x7fffu + ((u >> 16) & 1u);
    return u >> 16;
}
__device__ __forceinline__ unsigned int pack_bf16(float a, float b) {
    return bf16_rne(a) | (bf16_rne(b) << 16);
}
__device__ __forceinline__ float bf16_lo(unsigned int u) { return __uint_as_float(u << 16); }
__device__ __forceinline__ float bf16_hi(unsigned int u) { return __uint_as_float(u & 0xffff0000u); }
__device__ __forceinline__ float bf16_val(unsigned int h) { return __uint_as_float(h << 16); }

__device__ __forceinline__ bf16x8 as_bf16x8(uint4 u) {
    union { uint4 u; bf16x8 b; } x; x.u = u; return x.b;
}

// ---------- wprep: W1/W2/W3 -> fragment-ordered double-bf16; zero cnt/state/hist/binctr + hb zero-rows ----------

static __global__ __launch_bounds__(256) void wprep_k(
        const float* __restrict__ W1, const float* __restrict__ W2, const float* __restrict__ W3,
        unsigned int* __restrict__ Bfrag,    // [6][8192]: h1,l1,h2,l2,h3,l3
        int* __restrict__ cnt, int zcount4,
        unsigned int* __restrict__ zrowA, unsigned int* __restrict__ zrowB) {
    int gid = blockIdx.x * 256 + threadIdx.x;
    for (int i = gid; i < zcount4; i += 24 * 256)
        ((uint4*)cnt)[i] = make_uint4(0u, 0u, 0u, 0u);
    if (blockIdx.x == 0 && threadIdx.x < 32) {
        unsigned int* zr = (threadIdx.x < 16) ? zrowA : zrowB;   // zero row n of hbA / hbB
        *(uint4*)&zr[(threadIdx.x & 15) * 4] = make_uint4(0u, 0u, 0u, 0u);
    }

    const int wsel = blockIdx.x >> 3;
    const float* W = (wsel == 0) ? W1 : (wsel == 1) ? W2 : W3;
    unsigned int* Bh = Bfrag + (size_t)(2 * wsel) * 8192;
    unsigned int* Bl = Bh + 8192;
    int tt = (blockIdx.x & 7) * 256 + threadIdx.x;   // 0..2047
    int lane = tt & 63, kc = (tt >> 6) & 3, c = tt >> 8;
    int m = lane & 15, quad = lane >> 4;
    int col = c * 16 + m;
    int k0 = kc * 32 + quad * 8;
    unsigned int h4[4], l4[4];
#pragma unroll
    for (int dd = 0; dd < 4; dd++) {
        float w0 = W[(k0 + 2 * dd) * D + col];
        float w1 = W[(k0 + 2 * dd + 1) * D + col];
        unsigned int h0 = bf16_rne(w0), h1 = bf16_rne(w1);
        unsigned int L0 = bf16_rne(w0 - bf16_val(h0));
        unsigned int L1 = bf16_rne(w1 - bf16_val(h1));
        h4[dd] = h0 | (h1 << 16);
        l4[dd] = L0 | (L1 << 16);
    }
    int base = ((c * 4 + kc) * 64 + lane) * 4;
    *(uint4*)&Bh[base] = make_uint4(h4[0], h4[1], h4[2], h4[3]);
    *(uint4*)&Bl[base] = make_uint4(l4[0], l4[1], l4[2], l4[3]);
}

// ---------- FAT1: gemm1 (Bh in 32KB LDS, Bl from L2) ∥ pass1 histogram/rank blocks ----------
// 32KB LDS -> 4 blocks/CU (32 waves/CU) for BOTH gemm and pass1 block ranges.

static __global__ __launch_bounds__(512) void fat1_k(
        const float* __restrict__ x, const unsigned int* __restrict__ Bfrag,
        unsigned int* __restrict__ hb, int n, int gb,
        const int* __restrict__ ei, int E,
        int* __restrict__ cnt, int* __restrict__ rank) {
    __shared__ uint4 Bs[2048];           // 32 KB: W1 hi fragments only
    const int tid = threadIdx.x;
    if ((int)blockIdx.x >= gb) {     // ---- pass1: 4 edges/thread, 2048/block ----
        int e0 = (((int)blockIdx.x - gb) * 512 + tid) * 4;
        if (((E & 3) == 0) && e0 + 3 < E) {
            int4 d = *(const int4*)&ei[E + e0];
            int4 r;
            r.x = atomicAdd(&cnt[d.x], 1);
            r.y = atomicAdd(&cnt[d.y], 1);
            r.z = atomicAdd(&cnt[d.z], 1);
            r.w = atomicAdd(&cnt[d.w], 1);
            *(int4*)&rank[e0] = r;
        } else {
            for (int e = e0; e < E && e < e0 + 4; e++)
                rank[e] = atomicAdd(&cnt[ei[E + e]], 1);
        }
        return;
    }
    // stage W1 hi fragments (32 KB) into LDS; lo stays in global (L2-hot)
    {
        const uint4* Bg = (const uint4*)Bfrag;
#pragma unroll
        for (int i = 0; i < 4; i++)
            Bs[tid + i * 512] = Bg[tid + i * 512];
    }
    // ---- gemm1: MFMA double-bf16, unscaled; 8 waves x 16 rows ----
    const int g = blockIdx.x;
    const int w = tid >> 6;              // 0..7
    const int lane = tid & 63;
    const int m = lane & 15, quad = lane >> 4;
    const int arow = g * 128 + w * 16 + m;
    const bool rok = arow < n;
    uint4 Ah[4], Al[4];
#pragma unroll
    for (int kc = 0; kc < 4; kc++) {
        float4 f0 = make_float4(0.f, 0.f, 0.f, 0.f), f1 = f0;
        if (rok) {
            f0 = *(const float4*)&x[(size_t)arow * D + kc * 32 + quad * 8];
            f1 = *(const float4*)&x[(size_t)arow * D + kc * 32 + quad * 8 + 4];
        }
        unsigned int h0 = bf16_rne(f0.x), h1 = bf16_rne(f0.y), h2 = bf16_rne(f0.z), h3 = bf16_rne(f0.w);
        unsigned int h4 = bf16_rne(f1.x), h5 = bf16_rne(f1.y), h6 = bf16_rne(f1.z), h7 = bf16_rne(f1.w);
        Ah[kc] = make_uint4(h0 | (h1 << 16), h2 | (h3 << 16), h4 | (h5 << 16), h6 | (h7 << 16));
        unsigned int g0 = bf16_rne(f0.x - bf16_val(h0)), g1 = bf16_rne(f0.y - bf16_val(h1));
        unsigned int g2 = bf16_rne(f0.z - bf16_val(h2)), g3 = bf16_rne(f0.w - bf16_val(h3));
        unsigned int g4 = bf16_rne(f1.x - bf16_val(h4)), g5 = bf16_rne(f1.y - bf16_val(h5));
        unsigned int g6 = bf16_rne(f1.z - bf16_val(h6)), g7 = bf16_rne(f1.w - bf16_val(h7));
        Al[kc] = make_uint4(g0 | (g1 << 16), g2 | (g3 << 16), g4 | (g5 << 16), g6 | (g7 << 16));
    }
    __syncthreads();
    const int erow0 = g * 128 + w * 16 + quad * 4;
    unsigned short* out = (unsigned short*)hb;
    const unsigned int* Blg = Bfrag + 8192;
#pragma unroll
    for (int c = 0; c < 8; c++) {
        f32x4 acc = {0.f, 0.f, 0.f, 0.f};
#pragma unroll
        for (int kc = 0; kc < 4; kc++) {
            uint4 bh = Bs[(c * 4 + kc) * 64 + lane];
            uint4 bl = *(const uint4*)&Blg[((c * 4 + kc) * 64 + lane) * 4];
            acc = __builtin_amdgcn_mfma_f32_16x16x32_bf16(as_bf16x8(Ah[kc]), as_bf16x8(bh), acc, 0, 0, 0);
            acc = __builtin_amdgcn_mfma_f32_16x16x32_bf16(as_bf16x8(Ah[kc]), as_bf16x8(bl), acc, 0, 0, 0);
            acc = __builtin_amdgcn_mfma_f32_16x16x32_bf16(as_bf16x8(Al[kc]), as_bf16x8(bh), acc, 0, 0, 0);
        }
        int col = c * 16 + m;
#pragma unroll
        for (int r = 0; r < 4; r++) {
            int rr = erow0 + r;
            if (rr < n)
                out[(size_t)rr * D + col] = (unsigned short)bf16_rne(acc[r]);
        }
    }
}

// ---------- Single-dispatch exclusive scan (decoupled lookback) + dinv + degree histogram ----------

static __global__ __launch_bounds__(256) void scan_k(
        const int* __restrict__ cnt, int n, int* __restrict__ state,
        int* __restrict__ rowptr, float* __restrict__ dinv,
        int* __restrict__ hist) {
    __shared__ int s[256];
    __shared__ int lh[64];
    __shared__ int sprefix;
    const int b = blockIdx.x;
    const int i = b * 256 + threadIdx.x;
    if (threadIdx.x < 64) lh[threadIdx.x] = 0;
    int v = (i < n) ? cnt[i] : 0;
    if (i < n) dinv[i] = rsqrtf((float)v + 1.0f);   // +1 self loop; deg >= 1 always
    s[threadIdx.x] = v;
    __syncthreads();
    if (i < n) atomicAdd(&lh[v < 63 ? v : 63], 1);
    for (int off = 1; off < 256; off <<= 1) {
        int t = ((int)threadIdx.x >= off) ? s[threadIdx.x - off] : 0;
        __syncthreads();
        s[threadIdx.x] += t;
        __syncthreads();
    }
    int incl = s[threadIdx.x];
    int total = s[255];
    if (threadIdx.x == 0) {
        if (b == 0) {
            atomicExch(&state[0], (total << 2) | 2);
            sprefix = 0;
        } else {
            atomicExch(&state[b], (total << 2) | 1);
            int run = 0;
            for (int j = b - 1; j >= 0; j--) {
                int p;
                do { p = atomicAdd(&state[j], 0); } while ((p & 3) == 0);
                run += (p >> 2);
                if ((p & 3) == 2) break;
            }
            atomicExch(&state[b], ((run + total) << 2) | 2);
            sprefix = run;
        }
    }
    __syncthreads();
    int pre = sprefix;
    if (i < n) {
        rowptr[i] = pre + incl - v;
        if (i == n - 1) rowptr[n] = pre + incl;
    }
    if (threadIdx.x < 64) {
        int c = lh[threadIdx.x];
        if (c) atomicAdd(&hist[threadIdx.x], c);
    }
}

// ---------- FAT2b: pass2 scatter ∥ in-place dinv scale of hbA ∥ perm counting-sort ----------

static __global__ __launch_bounds__(256) void fat2b_k(
        unsigned int* __restrict__ hb, const float* __restrict__ dinv, int n,
        int p2b, int sb,
        const int* __restrict__ ei, int E,
        const int* __restrict__ rank, const int* __restrict__ rowptr,
        int* __restrict__ csr_src,
        const int* __restrict__ cnt, const int* __restrict__ hist,
        int* __restrict__ binctr, int* __restrict__ perm) {
    const int tid = threadIdx.x;
    int bb = (int)blockIdx.x;
    if (bb < p2b) {          // ---- pass2: no-atomic scatter, 2 edges/thread ----
        int e0 = (bb * 256 + tid) * 2;
        if (e0 + 1 < E) {
            int2 s2 = *(const int2*)&ei[e0];
            int2 d2 = *(const int2*)&ei[E + e0];
            int2 r2 = *(const int2*)&rank[e0];
            csr_src[rowptr[d2.x] + r2.x] = s2.x;
            csr_src[rowptr[d2.y] + r2.y] = s2.y;
        } else if (e0 < E) {
            csr_src[rowptr[ei[E + e0]] + rank[e0]] = ei[e0];
        }
        return;
    }
    bb -= p2b;
    if (bb < sb) {           // ---- scale: hbA row r *= dinv[r] (in place, uint4 = 8 bf16) ----
        int i4 = bb * 256 + tid;
        if (i4 < n * 16) {
            float d = dinv[i4 >> 4];
            uint4 v = ((const uint4*)hb)[i4];
            v.x = pack_bf16(bf16_lo(v.x) * d, bf16_hi(v.x) * d);
            v.y = pack_bf16(bf16_lo(v.y) * d, bf16_hi(v.y) * d);
            v.z = pack_bf16(bf16_lo(v.z) * d, bf16_hi(v.z) * d);
            v.w = pack_bf16(bf16_lo(v.w) * d, bf16_hi(v.w) * d);
            ((uint4*)hb)[i4] = v;
        }
        return;
    }
    bb -= sb;
    // ---- permscatter: descending-degree counting sort (two-level, low contention) ----
    __shared__ int loff[64], lcnt[64], lbase[64];
    if (tid < 64) {
        int ssum = 0;                         // descending: heavy bins first (LPT)
        for (int j = tid + 1; j < 64; j++) ssum += hist[j];
        loff[tid] = ssum;
        lcnt[tid] = 0;
    }
    __syncthreads();
    int i = bb * 256 + tid;
    int bin = 0, lrank = 0;
    if (i < n) {
        int dg = cnt[i];
        bin = dg < 63 ? dg : 63;
        lrank = atomicAdd(&lcnt[bin], 1);
    }
    __syncthreads();
    if (tid < 64 && lcnt[tid]) lbase[tid] = atomicAdd(&binctr[tid], lcnt[tid]);
    __syncthreads();
    if (i < n) perm[loff[bin] + lbase[bin] + lrank] = i;
}

// ---------- gather core: bulk int4 idx + sched_barrier-pinned gathers ----------

__device__ __forceinline__ void gather_accum8(
        const unsigned int* __restrict__ hbin, const int* __restrict__ csr,
        int beg, int deg, int n, int l,
        float& a0, float& a1, float& a2, float& a3,
        float& a4, float& a5, float& a6, float& a7) {
    const int nbat = (deg + 7) >> 3;
    int4 iA = *(const int4*)&csr[beg];        // pad-safe (csr has +64 ints slack)
    int4 iB = *(const int4*)&csr[beg + 4];
    for (int t = 0; t < nbat; t++) {
        const int q = t * 8;
        int s[8];
        s[0] = (q + 0 < deg) ? iA.x : n;
        s[1] = (q + 1 < deg) ? iA.y : n;
        s[2] = (q + 2 < deg) ? iA.z : n;
        s[3] = (q + 3 < deg) ? iA.w : n;
        s[4] = (q + 4 < deg) ? iB.x : n;
        s[5] = (q + 5 < deg) ? iB.y : n;
        s[6] = (q + 6 < deg) ? iB.z : n;
        s[7] = (q + 7 < deg) ? iB.w : n;
        uint4 v[8];
#pragma unroll
        for (int i = 0; i < 8; i++)
            v[i] = *(const uint4*)&hbin[(size_t)s[i] * 64 + l * 4];
        iA = *(const int4*)&csr[beg + q + 8];     // prefetch next batch (pad-safe)
        iB = *(const int4*)&csr[beg + q + 12];
        __builtin_amdgcn_sched_barrier(0);
#pragma unroll
        for (int i = 0; i < 8; i++) {
            a0 += bf16_lo(v[i].x); a1 += bf16_hi(v[i].x);
            a2 += bf16_lo(v[i].y); a3 += bf16_hi(v[i].y);
            a4 += bf16_lo(v[i].z); a5 += bf16_hi(v[i].z);
            a6 += bf16_lo(v[i].w); a7 += bf16_hi(v[i].w);
        }
    }
}

// ---------- FUSED agg + MFMA gemm: quarter-wave gathers (4 nodes/wave, uint4 = 16B/lane) ----------

static __global__ __launch_bounds__(256) void aggemm_k(
        const unsigned int* __restrict__ hbin,        // (n+1) rows, row n == 0
        const float* __restrict__ dinv,
        const int* __restrict__ rowptr, const int* __restrict__ csr,
        const int* __restrict__ perm,
        const float* __restrict__ bias,               // bias of PREV conv
        const unsigned int* __restrict__ Bh,          // next W, frag-ordered hi
        const unsigned int* __restrict__ Bl,          //             lo
        unsigned int* __restrict__ hbout, int n) {
    __shared__ unsigned int xs[16 * 68];   // 16 rows x 64 uints + 4 pad
    __shared__ int pms[16];
    __shared__ float pdv[16];
    const int tid = threadIdx.x;
    const int wv = tid >> 6;               // 0..3
    const int lane = tid & 63;
    const int l = lane & 15;               // lane in quarter
    const int lslot = wv * 4 + (lane >> 4);  // local node slot 0..15
    const int slot = blockIdx.x * 16 + lslot;
    const int node = (slot < n) ? perm[slot] : -1;
    if (l == 0) {
        pms[lslot] = node;
        pdv[lslot] = (node >= 0) ? dinv[node] : 0.f;
    }

    if (node >= 0) {
        const int beg = rowptr[node];
        const int deg = rowptr[node + 1] - beg;
        float a0 = 0.f, a1 = 0.f, a2 = 0.f, a3 = 0.f;
        float a4 = 0.f, a5 = 0.f, a6 = 0.f, a7 = 0.f;
        gather_accum8(hbin, csr, beg, deg, n, l, a0, a1, a2, a3, a4, a5, a6, a7);
        uint4 hv = *(const uint4*)&hbin[(size_t)node * 64 + l * 4];
        a0 += bf16_lo(hv.x); a1 += bf16_hi(hv.x);
        a2 += bf16_lo(hv.y); a3 += bf16_hi(hv.y);
        a4 += bf16_lo(hv.z); a5 += bf16_hi(hv.z);
        a6 += bf16_lo(hv.w); a7 += bf16_hi(hv.w);
        const float di = dinv[node];
        float4 b0 = *(const float4*)&bias[l * 8];
        float4 b1 = *(const float4*)&bias[l * 8 + 4];
        float o0 = fmaxf(fmaf(di, a0, b0.x), 0.f);
        float o1 = fmaxf(fmaf(di, a1, b0.y), 0.f);
        float o2 = fmaxf(fmaf(di, a2, b0.z), 0.f);
        float o3 = fmaxf(fmaf(di, a3, b0.w), 0.f);
        float o4 = fmaxf(fmaf(di, a4, b1.x), 0.f);
        float o5 = fmaxf(fmaf(di, a5, b1.y), 0.f);
        float o6 = fmaxf(fmaf(di, a6, b1.z), 0.f);
        float o7 = fmaxf(fmaf(di, a7, b1.w), 0.f);
        uint4 pw;
        pw.x = pack_bf16(o0, o1);
        pw.y = pack_bf16(o2, o3);
        pw.z = pack_bf16(o4, o5);
        pw.w = pack_bf16(o6, o7);
        *(uint4*)&xs[lslot * 68 + 4 * l] = pw;
    } else {
        *(uint4*)&xs[lslot * 68 + 4 * l] = make_uint4(0u, 0u, 0u, 0u);
    }
    __syncthreads();

    // ---- gemm phase: wave wv -> col groups c = 2wv, 2wv+1 ----
    const int m = lane & 15, quad = lane >> 4;
    uint4 A[4];
#pragma unroll
    for (int kc = 0; kc < 4; kc++)
        A[kc] = *(const uint4*)&xs[m * 68 + kc * 16 + quad * 4];
    unsigned short* out = (unsigned short*)hbout;
#pragma unroll
    for (int cc = 0; cc < 2; cc++) {
        const int c = wv * 2 + cc;
        f32x4 acc = {0.f, 0.f, 0.f, 0.f};
#pragma unroll
        for (int kc = 0; kc < 4; kc++) {
            int base = ((c * 4 + kc) * 64 + lane) * 4;
            uint4 bh = *(const uint4*)&Bh[base];
            uint4 bl = *(const uint4*)&Bl[base];
            acc = __builtin_amdgcn_mfma_f32_16x16x32_bf16(as_bf16x8(A[kc]), as_bf16x8(bh), acc, 0, 0, 0);
            acc = __builtin_amdgcn_mfma_f32_16x16x32_bf16(as_bf16x8(A[kc]), as_bf16x8(bl), acc, 0, 0, 0);
        }
        const int col = c * 16 + m;
#pragma unroll
        for (int r = 0; r < 4; r++) {
            int ls = quad * 4 + r;
            int nd = pms[ls];
            if (nd >= 0)
                out[(size_t)nd * D + col] = (unsigned short)bf16_rne(acc[r] * pdv[ls]);
        }
    }
}

// ---------- Final aggregation (layer 3): quarter-wave, 16 nodes/block ----------

static __global__ __launch_bounds__(256) void agg_k(const unsigned int* __restrict__ hb,
                                                    const float* __restrict__ dinv,
                                                    const int* __restrict__ rowptr,
                                                    const int* __restrict__ csr,
                                                    const int* __restrict__ perm,
                                                    const float* __restrict__ b,
                                                    unsigned int* __restrict__ outp, int n) {
    const int tid = threadIdx.x;
    const int wv = tid >> 6;
    const int lane = tid & 63;
    const int l = lane & 15;
    const int slot = blockIdx.x * 16 + wv * 4 + (lane >> 4);
    const int node = (slot < n) ? perm[slot] : -1;
    if (node < 0) return;

    const int beg = rowptr[node];
    const int deg = rowptr[node + 1] - beg;
    float a0 = 0.f, a1 = 0.f, a2 = 0.f, a3 = 0.f;
    float a4 = 0.f, a5 = 0.f, a6 = 0.f, a7 = 0.f;
    gather_accum8(hb, csr, beg, deg, n, l, a0, a1, a2, a3, a4, a5, a6, a7);
    uint4 hv = *(const uint4*)&hb[(size_t)node * 64 + l * 4];
    a0 += bf16_lo(hv.x); a1 += bf16_hi(hv.x);
    a2 += bf16_lo(hv.y); a3 += bf16_hi(hv.y);
    a4 += bf16_lo(hv.z); a5 += bf16_hi(hv.z);
    a6 += bf16_lo(hv.w); a7 += bf16_hi(hv.w);
    const float di = dinv[node];
    float4 b0 = *(const float4*)&b[l * 8];
    float4 b1 = *(const float4*)&b[l * 8 + 4];
    uint4 p;
    p.x = pack_bf16(fmaxf(fmaf(di, a0, b0.x), 0.f), fmaxf(fmaf(di, a1, b0.y), 0.f));
    p.y = pack_bf16(fmaxf(fmaf(di, a2, b0.z), 0.f), fmaxf(fmaf(di, a3, b0.w), 0.f));
    p.z = pack_bf16(fmaxf(fmaf(di, a4, b1.x), 0.f), fmaxf(fmaf(di, a5, b1.y), 0.f));
    p.w = pack_bf16(fmaxf(fmaf(di, a6, b1.z), 0.f), fmaxf(fmaf(di, a7, b1.w), 0.f));
    *(uint4*)&outp[(size_t)node * 64 + l * 4] = p;
}

// ---------- Fused mean-pool + classifier (uint4-vectorized pooling) ----------

static __global__ __launch_bounds__(256) void poolcls_k(const unsigned int* __restrict__ xp,
                                                        const int* __restrict__ batch, int n,
                                                        const float* __restrict__ Wc,
                                                        const float* __restrict__ bc,
                                                        const float* __restrict__ Wo,
                                                        const float* __restrict__ bo,
                                                        float* __restrict__ out) {
    int g = blockIdx.x;
    int lo = 0, hi = n;
    while (lo < hi) { int m = (lo + hi) >> 1; if (batch[m] < g) lo = m + 1; else hi = m; }
    int start = lo;
    hi = n;
    while (lo < hi) { int m = (lo + hi) >> 1; if (batch[m] < g + 1) lo = m + 1; else hi = m; }
    int end = lo;

    const int rl = threadIdx.x >> 4;     // row lane 0..15
    const int fg = threadIdx.x & 15;     // feature group (8 feats)
    float a0 = 0.f, a1 = 0.f, a2 = 0.f, a3 = 0.f;
    float a4 = 0.f, a5 = 0.f, a6 = 0.f, a7 = 0.f;
    for (int r = start + rl; r < end; r += 16) {
        uint4 v = *(const uint4*)&xp[(size_t)r * 64 + fg * 4];
        a0 += bf16_lo(v.x); a1 += bf16_hi(v.x);
        a2 += bf16_lo(v.y); a3 += bf16_hi(v.y);
        a4 += bf16_lo(v.z); a5 += bf16_hi(v.z);
        a6 += bf16_lo(v.w); a7 += bf16_hi(v.w);
    }
    __shared__ float red[16][130];
    __shared__ float pooled[D];
    float* rr = &red[rl][fg * 8];
    rr[0] = a0; rr[1] = a1; rr[2] = a2; rr[3] = a3;
    rr[4] = a4; rr[5] = a5; rr[6] = a6; rr[7] = a7;
    __syncthreads();
    int f = threadIdx.x;
    if (f < D) {
        float tot = 0.f;
#pragma unroll
        for (int j = 0; j < 16; j++) tot += red[j][f];
        float c = (float)(end - start);
        pooled[f] = tot / fmaxf(c, 1.0f);
    }
    __syncthreads();
    if (f < H) {
        float z = bc[f];
#pragma unroll
        for (int k = 0; k < D; k++) z = fmaf(pooled[k], Wc[k * H + f], z);
        z = fmaxf(z, 0.f);
        float v = z * Wo[f];
        for (int off = 32; off > 0; off >>= 1) v += __shfl_down(v, off);
        if (f == 0) out[g] = v + bo[0];
    }
}

// ---------- Orchestration ----------

extern "C" void kernel_launch(void* const* d_in, const int* in_sizes, int n_in,
                              void* d_out, int out_size, void* d_ws, size_t ws_size,
                              hipStream_t stream) {
    const float* x     = (const float*)d_in[0];
    const int*   ei    = (const int*)d_in[1];
    const int*   batch = (const int*)d_in[2];
    const float* W1 = (const float*)d_in[3];
    const float* b1 = (const float*)d_in[4];
    const float* W2 = (const float*)d_in[5];
    const float* b2 = (const float*)d_in[6];
    const float* W3 = (const float*)d_in[7];
    const float* b3 = (const float*)d_in[8];
    const float* Wc = (const float*)d_in[9];
    const float* bc = (const float*)d_in[10];
    const float* Wo = (const float*)d_in[11];
    const float* bo = (const float*)d_in[12];

    const int n = in_sizes[0] / D;
    const int E = in_sizes[1] / 2;
    const int G = out_size;

    char* ws = (char*)d_ws;
    size_t off = 0;
    auto alloc = [&](size_t bytes) -> void* {
        void* p = ws + off;
        off = (off + bytes + 255) & ~(size_t)255;
        return p;
    };
    int*   cnt     = (int*)alloc((size_t)n * 4 + 4096);
    int*   state   = cnt + n;                       // lookback state (NB ints)
    int*   hist    = state + 256;                   // 64-bin degree histogram
    int*   binctr  = hist + 64;                     // counting-sort counters
    int*   rowptr  = (int*)alloc((size_t)(n + 1) * 4);
    float* dinv    = (float*)alloc((size_t)n * 4);
    int*   rank    = (int*)alloc((size_t)E * 4);
    int*   csr_src = (int*)alloc((size_t)E * 4 + 256);   // +64 ints pad for bulk idx loads
    int*   perm    = (int*)alloc((size_t)n * 4);
    unsigned int* hbA = (unsigned int*)alloc((size_t)(n + 1) * (D / 2) * 4);  // +1 zero row
    unsigned int* hbB = (unsigned int*)alloc((size_t)(n + 1) * (D / 2) * 4);
    unsigned int* Bfrag = (unsigned int*)alloc(6 * 8192 * 4);                 // h1,l1,h2,l2,h3,l3
    (void)ws_size; (void)n_in;

    const int NB = (n + 255) / 256;
    const int GB = (n + 127) / 128;                 // fat1 gemm blocks (128 rows each)
    const int P1 = (E + 2047) / 2048;               // fat1 pass1 blocks (512 thr x 4 edges)
    const int P2 = (E + 511) / 512;
    const int SB = (n * 16 + 255) / 256;            // scale blocks (uint4 per thread)
    const int PP = (n + 255) / 256;
    const int ag16 = (n + 15) / 16;
    const int zcount4 = (n + 1024) / 4;

    // W prep + zero cnt/state/hist/binctr + zero rows n of hbA/hbB
    wprep_k<<<24, 256, 0, stream>>>(W1, W2, W3, Bfrag, cnt, zcount4,
                                    hbA + (size_t)n * 64, hbB + (size_t)n * 64);

    // gemm1 (Bh in LDS, Bl from L2) ∥ pass1 histogram+rank
    fat1_k<<<GB + P1, 512, 0, stream>>>(x, Bfrag, hbA, n, GB, ei, E, cnt, rank);

    // rowptr scan + dinv + degree-bin histogram
    scan_k<<<NB, 256, 0, stream>>>(cnt, n, state, rowptr, dinv, hist);

    // pass2 scatter ∥ hbA in-place dinv scale ∥ degree counting-sort perm
    fat2b_k<<<P2 + SB + PP, 256, 0, stream>>>(hbA, dinv, n, P2, SB,
                                              ei, E, rank, rowptr, csr_src,
                                              cnt, hist, binctr, perm);

    // layer boundaries: fused agg(prev) + gemm(next W); all pre-scaled bf16
    aggemm_k<<<ag16, 256, 0, stream>>>(hbA, dinv, rowptr, csr_src, perm, b1,
                                       Bfrag + 2 * 8192, Bfrag + 3 * 8192, hbB, n);
    aggemm_k<<<ag16, 256, 0, stream>>>(hbB, dinv, rowptr, csr_src, perm, b2,
                                       Bfrag + 4 * 8192, Bfrag + 5 * 8192, hbA, n);

    // final aggregation + pooled classifier
    agg_k<<<ag16, 256, 0, stream>>>(hbA, dinv, rowptr, csr_src, perm, b3, hbB, n);
    poolcls_k<<<G, 256, 0, stream>>>(hbB, batch, n, Wc, bc, Wo, bo, (float*)d_out);
}